// Round 3
// baseline (413.872 us; speedup 1.0000x reference)
//
#include <hip/hip_runtime.h>
#include <math.h>
#include <stdint.h>

// Problem constants
#define BB 4
#define DIM 192
#define HEADS 4
#define CH 48            // DIM/HEADS
#define HW 16384         // 128*128
#define C3 576           // 3*DIM
#define NCHUNK 64        // attention n-chunks (chunk = 256 cols)

typedef unsigned short ushort_t;
typedef __attribute__((ext_vector_type(8))) short short8;
typedef __attribute__((ext_vector_type(4))) float floatx4;

__device__ __forceinline__ float bf2f(unsigned int u) {
    union { unsigned int i; float f; } v; v.i = u << 16; return v.f;
}
__device__ __forceinline__ ushort_t f2bf(float f) {  // RNE
    union { float f; unsigned int i; } v; v.f = f;
    unsigned int x = v.i;
    x += 0x7fffu + ((x >> 16) & 1u);
    return (ushort_t)(x >> 16);
}

__global__ __launch_bounds__(256) void zero_init(float* __restrict__ p, int n) {
    int i = blockIdx.x * 256 + threadIdx.x;
    if (i < n) p[i] = 0.f;
}

// ---------------- weights fp32 -> (hi, lo) bf16 pair ----------------
__global__ __launch_bounds__(256) void convert_split(
    const float* __restrict__ in, ushort_t* __restrict__ hi,
    ushort_t* __restrict__ lo, int n)
{
    int i = blockIdx.x * 256 + threadIdx.x;
    if (i < n) {
        float f = in[i];
        ushort_t h = f2bf(f);
        hi[i] = h;
        lo[i] = f2bf(f - bf2f(h));
    }
}

// ---------------- transpose + split-convert: fp32 [192][16384] -> bf16 [16384][192] hi,lo ----------------
__global__ __launch_bounds__(256) void tconv(
    const float* __restrict__ in, ushort_t* __restrict__ out_hi,
    ushort_t* __restrict__ out_lo, long inStride)
{
    int z = blockIdx.z;
    in += (long)z * inStride;
    out_hi += (long)z * HW * DIM;
    out_lo += (long)z * HW * DIM;
    __shared__ ushort_t th[64][80];
    __shared__ ushort_t tl[64][80];
    int n0 = blockIdx.x * 64, k0 = blockIdx.y * 64;
    int t = threadIdx.x;
#pragma unroll
    for (int i = 0; i < 4; ++i) {
        int kl = (t >> 4) + 16 * i;
        float4 v = *(const float4*)(in + (long)(k0 + kl) * HW + n0 + (t & 15) * 4);
        int nl = (t & 15) * 4;
        ushort_t hx = f2bf(v.x), hy = f2bf(v.y), hz = f2bf(v.z), hw = f2bf(v.w);
        th[nl + 0][kl] = hx; th[nl + 1][kl] = hy;
        th[nl + 2][kl] = hz; th[nl + 3][kl] = hw;
        tl[nl + 0][kl] = f2bf(v.x - bf2f(hx));
        tl[nl + 1][kl] = f2bf(v.y - bf2f(hy));
        tl[nl + 2][kl] = f2bf(v.z - bf2f(hz));
        tl[nl + 3][kl] = f2bf(v.w - bf2f(hw));
    }
    __syncthreads();
#pragma unroll
    for (int i = 0; i < 2; ++i) {
        int nl = t >> 2, seg = (t & 3) + 4 * i;
        *(uint4*)(out_hi + (long)(n0 + nl) * DIM + k0 + seg * 8) = *(uint4*)&th[nl][seg * 8];
        *(uint4*)(out_lo + (long)(n0 + nl) * DIM + k0 + seg * 8) = *(uint4*)&tl[nl][seg * 8];
    }
}

// ---------------- bf16 transpose: [192][16384] -> [16384][192] ----------------
__global__ __launch_bounds__(256) void tconv_b16(
    const ushort_t* __restrict__ in, ushort_t* __restrict__ out)
{
    int z = blockIdx.z;
    in  += (long)z * DIM * HW;
    out += (long)z * HW * DIM;
    __shared__ ushort_t th[64][80];
    int n0 = blockIdx.x * 64, k0 = blockIdx.y * 64;
    int t = threadIdx.x;
#pragma unroll
    for (int i = 0; i < 4; ++i) {
        int kl = (t >> 4) + 16 * i;
        uint2 v = *(const uint2*)(in + (long)(k0 + kl) * HW + n0 + (t & 15) * 4);
        int nl = (t & 15) * 4;
        th[nl + 0][kl] = (ushort_t)(v.x & 0xffffu);
        th[nl + 1][kl] = (ushort_t)(v.x >> 16);
        th[nl + 2][kl] = (ushort_t)(v.y & 0xffffu);
        th[nl + 3][kl] = (ushort_t)(v.y >> 16);
    }
    __syncthreads();
#pragma unroll
    for (int i = 0; i < 2; ++i) {
        int nl = t >> 2, seg = (t & 3) + 4 * i;
        *(uint4*)(out + (long)(n0 + nl) * DIM + k0 + seg * 8) = *(uint4*)&th[nl][seg * 8];
    }
}

// ---------------- register-direct MFMA GEMM, K=192 fixed, batched over z ----------------
// NO LDS, NO barriers: A and B fragments load straight from global (bf16 n-major
// rows == MFMA fragment layout, same pattern as attn_mfma). BM=64 x BN=128,
// 4 waves (2m x 2n), each wave 32x64 = acc[2][4].
template<int TERMS>
__global__ __launch_bounds__(256) void gemm_reg(
    const ushort_t* __restrict__ Ahi, const ushort_t* __restrict__ Alo,
    const ushort_t* __restrict__ BThi, const ushort_t* __restrict__ BTlo,
    float* __restrict__ C, int M, int N,
    long strideA, long strideB, long strideC)
{
    int z = blockIdx.z;
    Ahi += z * strideA; Alo += z * strideA;
    BThi += z * strideB; BTlo += z * strideB;
    C += z * strideC;
    int t = threadIdx.x;
    int wave = t >> 6, lane = t & 63;
    int l15 = lane & 15, quad = lane >> 4;
    int m0 = blockIdx.y * 64, n0 = blockIdx.x * 128;
    int wm = (wave & 1) * 32, wn = (wave >> 1) * 64;

    // per-lane row base pointers (compile-time indexed -> stay in registers)
    const ushort_t* bph[4];
    const ushort_t* bpl[4];
#pragma unroll
    for (int ni = 0; ni < 4; ++ni) {
        long ro = (long)(n0 + wn + ni * 16 + l15) * 192;
        bph[ni] = BThi + ro;
        bpl[ni] = BTlo + ro;
    }
    const ushort_t* aph[2];
    const ushort_t* apl[2];
#pragma unroll
    for (int mi = 0; mi < 2; ++mi) {
        long ro = (long)(m0 + wm + mi * 16 + l15) * 192;
        aph[mi] = Ahi + ro;
        apl[mi] = Alo + ro;
    }

    floatx4 acc[2][4];
#pragma unroll
    for (int i = 0; i < 2; ++i)
#pragma unroll
        for (int j = 0; j < 4; ++j) acc[i][j] = (floatx4){0.f, 0.f, 0.f, 0.f};

    if (TERMS == 1) {
        short8 af[2][6];
#pragma unroll
        for (int mi = 0; mi < 2; ++mi)
#pragma unroll
            for (int k0 = 0; k0 < 6; ++k0)
                af[mi][k0] = *(const short8*)(aph[mi] + k0 * 32 + quad * 8);
#pragma unroll
        for (int k0 = 0; k0 < 6; ++k0) {
            int col = k0 * 32 + quad * 8;
            short8 bf[4];
#pragma unroll
            for (int ni = 0; ni < 4; ++ni)
                bf[ni] = *(const short8*)(bph[ni] + col);
#pragma unroll
            for (int mi = 0; mi < 2; ++mi)
#pragma unroll
                for (int ni = 0; ni < 4; ++ni)
                    acc[mi][ni] = __builtin_amdgcn_mfma_f32_16x16x32_bf16(
                        af[mi][k0], bf[ni], acc[mi][ni], 0, 0, 0);
        }
    } else {
#pragma unroll
        for (int kh = 0; kh < 2; ++kh) {
            short8 ah[2][3], al[2][3];
#pragma unroll
            for (int mi = 0; mi < 2; ++mi)
#pragma unroll
                for (int k0 = 0; k0 < 3; ++k0) {
                    int col = kh * 96 + k0 * 32 + quad * 8;
                    ah[mi][k0] = *(const short8*)(aph[mi] + col);
                    al[mi][k0] = *(const short8*)(apl[mi] + col);
                }
#pragma unroll
            for (int k0 = 0; k0 < 3; ++k0) {
                int col = kh * 96 + k0 * 32 + quad * 8;
                short8 bh[4], bl[4];
#pragma unroll
                for (int ni = 0; ni < 4; ++ni) {
                    bh[ni] = *(const short8*)(bph[ni] + col);
                    bl[ni] = *(const short8*)(bpl[ni] + col);
                }
#pragma unroll
                for (int mi = 0; mi < 2; ++mi)
#pragma unroll
                    for (int ni = 0; ni < 4; ++ni) {
                        acc[mi][ni] = __builtin_amdgcn_mfma_f32_16x16x32_bf16(
                            ah[mi][k0], bh[ni], acc[mi][ni], 0, 0, 0);
                        acc[mi][ni] = __builtin_amdgcn_mfma_f32_16x16x32_bf16(
                            ah[mi][k0], bl[ni], acc[mi][ni], 0, 0, 0);
                        acc[mi][ni] = __builtin_amdgcn_mfma_f32_16x16x32_bf16(
                            al[mi][k0], bh[ni], acc[mi][ni], 0, 0, 0);
                    }
            }
        }
    }
#pragma unroll
    for (int mi = 0; mi < 2; ++mi)
#pragma unroll
        for (int ni = 0; ni < 4; ++ni) {
            long base = (long)(m0 + wm + mi * 16 + quad * 4) * N + n0 + wn + ni * 16 + l15;
#pragma unroll
            for (int r = 0; r < 4; ++r)
                C[base + (long)r * N] = acc[mi][ni][r];
        }
}

// ---------------- Depthwise 3x3 + fused sum-of-squares ----------------
// q,k channels (gc < 2*DIM) -> bf16 hi/lo planes [z][384][HW] (feeds MFMA QK^T)
// v channels   (gc >= 2*DIM) -> bf16 vbuf16 [z][192][HW]
__global__ __launch_bounds__(256) void dwconv3x3_lds(
    const float* __restrict__ in, const float* __restrict__ w,
    ushort_t* __restrict__ qk_hi, ushort_t* __restrict__ qk_lo,
    ushort_t* __restrict__ vbuf16, float* __restrict__ normsq,
    int c0, int chunk)
{
    __shared__ float tile[10][132];
    int z = blockIdx.z;
    int cl = blockIdx.y;
    int gc = c0 + cl;
    in  += (long)z * chunk * HW + (long)cl * HW;
    int y0 = blockIdx.x * 8;
    const float* wc = w + gc * 9;
    float wf[9];
#pragma unroll
    for (int i = 0; i < 9; ++i) wf[i] = wc[i];
    int t = threadIdx.x;
    if (t < 10) { tile[t][0] = 0.f; tile[t][129] = 0.f; }
    for (int i = t; i < 320; i += 256) {
        int r = i >> 5, c4 = (i & 31) * 4;
        int gy = y0 - 1 + r;
        float4 v = {0.f, 0.f, 0.f, 0.f};
        if (gy >= 0 && gy < 128) v = *(const float4*)(in + gy * 128 + c4);
        tile[r][1 + c4] = v.x; tile[r][2 + c4] = v.y;
        tile[r][3 + c4] = v.z; tile[r][4 + c4] = v.w;
    }
    __syncthreads();
    int yl = t >> 5, xl = (t & 31) * 4;
    float s0 = 0.f, s1 = 0.f, s2 = 0.f, s3 = 0.f;
#pragma unroll
    for (int r = 0; r < 3; ++r) {
        float c0v = tile[yl + r][xl + 0], c1v = tile[yl + r][xl + 1];
        float c2v = tile[yl + r][xl + 2], c3v = tile[yl + r][xl + 3];
        float c4v = tile[yl + r][xl + 4], c5v = tile[yl + r][xl + 5];
        float w0 = wf[r * 3], w1 = wf[r * 3 + 1], w2 = wf[r * 3 + 2];
        s0 += w0 * c0v + w1 * c1v + w2 * c2v;
        s1 += w0 * c1v + w1 * c2v + w2 * c3v;
        s2 += w0 * c2v + w1 * c3v + w2 * c4v;
        s3 += w0 * c3v + w1 * c4v + w2 * c5v;
    }
    long pix = (long)(y0 + yl) * 128 + xl;
    ushort_t h0 = f2bf(s0), h1 = f2bf(s1), h2 = f2bf(s2), h3 = f2bf(s3);
    uint2 ph;
    ph.x = (unsigned)h0 | ((unsigned)h1 << 16);
    ph.y = (unsigned)h2 | ((unsigned)h3 << 16);
    if (gc < 2 * DIM) {
        ushort_t l0 = f2bf(s0 - bf2f(h0)), l1 = f2bf(s1 - bf2f(h1));
        ushort_t l2 = f2bf(s2 - bf2f(h2)), l3 = f2bf(s3 - bf2f(h3));
        uint2 pl;
        pl.x = (unsigned)l0 | ((unsigned)l1 << 16);
        pl.y = (unsigned)l2 | ((unsigned)l3 << 16);
        long rbase = ((long)z * 384 + gc) * HW + pix;
        *(uint2*)(qk_hi + rbase) = ph;
        *(uint2*)(qk_lo + rbase) = pl;
        __syncthreads();
        float* red = (float*)tile;
        red[t] = s0 * s0 + s1 * s1 + s2 * s2 + s3 * s3;
        __syncthreads();
        for (int off = 128; off > 0; off >>= 1) {
            if (t < off) red[t] += red[t + off];
            __syncthreads();
        }
        if (t == 0) atomicAdd(&normsq[z * 512 + gc], red[0]);
    } else {
        *(uint2*)(vbuf16 + ((long)z * DIM + (gc - 2 * DIM)) * HW + pix) = ph;
    }
}

// ---------------- QK^T partials via MFMA, 3-term bf16 hi/lo ----------------
// grid (NCHUNK, HEADS, BB), block 256 = 4 waves; block covers 256 n-cols,
// each wave 64 cols (2 k-steps of 32). Cross-wave reduce in LDS, one partial/block.
__global__ __launch_bounds__(256) void attn_mfma(
    const ushort_t* __restrict__ qk_hi, const ushort_t* __restrict__ qk_lo,
    float* __restrict__ partial)
{
    int z = blockIdx.z, h = blockIdx.y, pidx = blockIdx.x;
    int t = threadIdx.x;
    int wave = t >> 6, lane = t & 63;
    int l15 = lane & 15, quad = lane >> 4;
    long base = (long)z * 384 * HW;
    const ushort_t* qh = qk_hi + base + (long)(h * CH) * HW;
    const ushort_t* ql = qk_lo + base + (long)(h * CH) * HW;
    const ushort_t* kh = qk_hi + base + (long)(DIM + h * CH) * HW;
    const ushort_t* kl = qk_lo + base + (long)(DIM + h * CH) * HW;
    int ncol0 = pidx * 256 + wave * 64;

    floatx4 acc[3][3];
#pragma unroll
    for (int i = 0; i < 3; ++i)
#pragma unroll
        for (int j = 0; j < 3; ++j) acc[i][j] = (floatx4){0.f, 0.f, 0.f, 0.f};

#pragma unroll
    for (int ks = 0; ks < 2; ++ks) {
        int col = ncol0 + ks * 32 + quad * 8;
        short8 ah[3], al[3], bh[3], bl[3];
#pragma unroll
        for (int i = 0; i < 3; ++i) {
            long ro = (long)(i * 16 + l15) * HW + col;
            ah[i] = *(const short8*)(qh + ro);
            al[i] = *(const short8*)(ql + ro);
            bh[i] = *(const short8*)(kh + ro);
            bl[i] = *(const short8*)(kl + ro);
        }
#pragma unroll
        for (int mi = 0; mi < 3; ++mi)
#pragma unroll
            for (int ni = 0; ni < 3; ++ni) {
                acc[mi][ni] = __builtin_amdgcn_mfma_f32_16x16x32_bf16(
                    ah[mi], bh[ni], acc[mi][ni], 0, 0, 0);
                acc[mi][ni] = __builtin_amdgcn_mfma_f32_16x16x32_bf16(
                    ah[mi], bl[ni], acc[mi][ni], 0, 0, 0);
                acc[mi][ni] = __builtin_amdgcn_mfma_f32_16x16x32_bf16(
                    al[mi], bh[ni], acc[mi][ni], 0, 0, 0);
            }
    }

    // cross-wave reduce: waves 0,1 store into sred[0],sred[1]; waves 2,3 add.
    __shared__ float sred[2][48 * 50];
    float* sb = sred[wave & 1];
    if (wave < 2) {
#pragma unroll
        for (int mi = 0; mi < 3; ++mi)
#pragma unroll
            for (int ni = 0; ni < 3; ++ni)
#pragma unroll
                for (int r = 0; r < 4; ++r)
                    sb[(mi * 16 + quad * 4 + r) * 50 + ni * 16 + l15] = acc[mi][ni][r];
    }
    __syncthreads();
    if (wave >= 2) {
#pragma unroll
        for (int mi = 0; mi < 3; ++mi)
#pragma unroll
            for (int ni = 0; ni < 3; ++ni)
#pragma unroll
                for (int r = 0; r < 4; ++r)
                    sb[(mi * 16 + quad * 4 + r) * 50 + ni * 16 + l15] += acc[mi][ni][r];
    }
    __syncthreads();
    float* pp = partial + ((long)(pidx * 16 + z * HEADS + h)) * 2304;
    for (int i = t; i < 2304; i += 256) {
        int row = i / 48, colo = i - row * 48;
        pp[i] = sred[0][row * 50 + colo] + sred[1][row * 50 + colo];
    }
}

// ---------------- top-k softmax combine: reduce partials inline; wave per row ----------------
// grid (48, BB), block 256 (4 waves = 4 rows)
__global__ __launch_bounds__(256) void topk_combine2(
    const float* __restrict__ partial, const float* __restrict__ normsq,
    const float* __restrict__ temp, const float* __restrict__ attn_w,
    float* __restrict__ Wc)
{
    int z = blockIdx.y;
    int wave = threadIdx.x >> 6, lane = threadIdx.x & 63;
    int rid = blockIdx.x * 4 + wave;   // 0..191 = h*48 + c
    int c = rid % CH, h = rid / CH;
    int d = lane;
    float a = -INFINITY;
    if (d < 48) {
        float s = 0.f;
        const float* pp = partial + (long)(z * HEADS + h) * 2304 + c * CH + d;
        for (int p = 0; p < NCHUNK; ++p) s += pp[(long)p * 16 * 2304];
        float invq = 1.0f / fmaxf(sqrtf(normsq[z * 512 + h * CH + c]), 1e-12f);
        float invk = 1.0f / fmaxf(sqrtf(normsq[z * 512 + DIM + h * CH + d]), 1e-12f);
        a = s * invq * invk * temp[h];
    }
    float m = a;
#pragma unroll
    for (int off = 32; off > 0; off >>= 1) m = fmaxf(m, __shfl_xor(m, off, 64));
    float e = (d < 48) ? expf(a - m) : 0.f;
    int rank = 0;
    for (int j = 0; j < 48; ++j) {
        float aj = __shfl(a, j, 64);
        rank += (aj > a) || (aj == a && j < d);
    }
    // k = int(48*rate) in IEEE double: {24, 32, 36, 38} (48*(2/3) rounds UP to 32.0)
    const int kv[4] = {24, 32, 36, 38};
    float s = 0.f;
#pragma unroll
    for (int i = 0; i < 4; ++i) {
        float contrib = (d < 48 && rank < kv[i]) ? e : 0.f;
#pragma unroll
        for (int off = 32; off > 0; off >>= 1) contrib += __shfl_xor(contrib, off, 64);
        s += (rank < kv[i]) ? attn_w[i] / contrib : 0.f;
    }
    if (d < 48) Wc[(long)z * 9216 + (long)rid * CH + d] = e * s;
}

// ---------------- M[z][o, h*48+d] = sum_ch wproj[o, h*48+ch] * Wc[z][h,ch,d] -> bf16 ----------------
__global__ __launch_bounds__(256) void build_m(
    const float* __restrict__ wproj, const float* __restrict__ Wc,
    ushort_t* __restrict__ Mb)
{
    int z = blockIdx.y;
    int idx = blockIdx.x * 256 + threadIdx.x;
    if (idx >= DIM * DIM) return;
    int cg = idx % DIM;
    int o  = idx / DIM;
    int h = cg / CH, d = cg % CH;
    const float* wp = wproj + o * DIM + h * CH;
    const float* wcc = Wc + (long)z * 9216 + (long)h * CH * CH + d;
    float s = 0.f;
#pragma unroll
    for (int ch = 0; ch < CH; ++ch) s += wp[ch] * wcc[ch * CH];
    Mb[(long)z * DIM * DIM + idx] = f2bf(s);
}

extern "C" void kernel_launch(void* const* d_in, const int* in_sizes, int n_in,
                              void* d_out, int out_size, void* d_ws, size_t ws_size,
                              hipStream_t stream) {
    const float* x      = (const float*)d_in[0];   // [4,192,128,128]
    const float* w_qkv  = (const float*)d_in[1];   // [576,192]
    const float* w_dw   = (const float*)d_in[2];   // [576,9]
    const float* w_proj = (const float*)d_in[3];   // [192,192]
    const float* temper = (const float*)d_in[4];   // [4]
    const float* attn_w = (const float*)d_in[5];   // [4]
    float* out = (float*)d_out;                    // [4,192,128,128]

    // Workspace. Total used ~227 MiB (chunk=192).
    char* p = (char*)d_ws;
    ushort_t* qk_hi  = (ushort_t*)p;   p += (long)BB * 384 * HW * 2;      // 50.3 MB
    ushort_t* qk_lo  = (ushort_t*)p;   p += (long)BB * 384 * HW * 2;      // 50.3 MB
    ushort_t* vbuf16 = (ushort_t*)p;   p += (long)BB * DIM * HW * 2;      // 25.2 MB
    ushort_t* xT_hi  = (ushort_t*)p;   p += (long)BB * HW * DIM * 2;      // 25.2 MB
    ushort_t* xT_lo  = (ushort_t*)p;   p += (long)BB * HW * DIM * 2;      // 25.2 MB
    ushort_t* wq_hi  = (ushort_t*)p;   p += (long)C3 * DIM * 2;
    ushort_t* wq_lo  = (ushort_t*)p;   p += (long)C3 * DIM * 2;
    float* normsq    = (float*)p;      p += (long)BB * 512 * 4;
    float* Wc        = (float*)p;      p += (long)BB * 9216 * 4;
    ushort_t* Mb     = (ushort_t*)p;   p += (long)BB * DIM * DIM * 2;
    float* pre       = (float*)p;      // BB * chunk * HW floats
    float* partial   = pre;            // alias: pre dead before attn_mfma runs (9.4 MB)
    long avail = (long)ws_size - (long)(p - (char*)d_ws);
    int chunk = 64;                                         // 16.8 MB fallback
    if (avail >= (long)BB * 192 * HW * 4) chunk = 192;      // 50.3 MB

    // 0a. zero normsq
    zero_init<<<(BB * 512 + 255) / 256, 256, 0, stream>>>(normsq, BB * 512);
    // 0b. weights -> split bf16
    convert_split<<<(C3 * DIM + 255) / 256, 256, 0, stream>>>(
        w_qkv, wq_hi, wq_lo, C3 * DIM);
    // 0c. x -> xT hi/lo bf16, all batches
    tconv<<<dim3(HW / 64, DIM / 64, BB), 256, 0, stream>>>(
        x, xT_hi, xT_lo, (long)DIM * HW);

    // 1+2. qkv 1x1 MFMA + dwconv3x3(+sumsq). q,k chunks: TERMS=3; v chunks: TERMS=1.
    for (int c0 = 0; c0 < C3; c0 += chunk) {
        if (c0 < 2 * DIM)
            gemm_reg<3><<<dim3(HW / 128, chunk / 64, BB), 256, 0, stream>>>(
                wq_hi + (long)c0 * DIM, wq_lo + (long)c0 * DIM, xT_hi, xT_lo,
                pre, chunk, HW, 0L, (long)HW * DIM, (long)chunk * HW);
        else
            gemm_reg<1><<<dim3(HW / 128, chunk / 64, BB), 256, 0, stream>>>(
                wq_hi + (long)c0 * DIM, wq_hi + (long)c0 * DIM, xT_hi, xT_hi,
                pre, chunk, HW, 0L, (long)HW * DIM, (long)chunk * HW);
        dwconv3x3_lds<<<dim3(16, chunk, BB), 256, 0, stream>>>(
            pre, w_dw, qk_hi, qk_lo, vbuf16, normsq, c0, chunk);
    }
    // 3. QK^T partials via MFMA (no atomics; 64 partials)
    attn_mfma<<<dim3(NCHUNK, HEADS, BB), 256, 0, stream>>>(qk_hi, qk_lo, partial);
    // 4. top-k softmax combine (reduce partials + norms inline)
    topk_combine2<<<dim3(48, BB), 256, 0, stream>>>(
        partial, normsq, temper, attn_w, Wc);
    // 5. fold proj into per-batch [192,192] bf16
    build_m<<<dim3((DIM * DIM + 255) / 256, BB), 256, 0, stream>>>(w_proj, Wc, Mb);
    // 6. v bf16 [ch][pix] -> vT bf16 [pix][ch] (reuse xT_hi)
    tconv_b16<<<dim3(HW / 64, DIM / 64, BB), 256, 0, stream>>>(vbuf16, xT_hi);
    // 7. out = M @ v (MFMA, single term)
    gemm_reg<1><<<dim3(HW / 128, DIM / 64, BB), 256, 0, stream>>>(
        Mb, Mb, xT_hi, xT_hi, out, DIM, HW,
        (long)DIM * DIM, (long)HW * DIM, (long)DIM * HW);
}

// Round 5
// 369.457 us; speedup vs baseline: 1.1202x; 1.1202x over previous
//
#include <hip/hip_runtime.h>
#include <math.h>
#include <stdint.h>

// Problem constants
#define BB 4
#define DIM 192
#define HEADS 4
#define CH 48            // DIM/HEADS
#define HW 16384         // 128*128
#define C3 576           // 3*DIM
#define NCHUNK 64        // attention n-chunks (chunk = 256 cols)

typedef unsigned short ushort_t;
typedef __attribute__((ext_vector_type(8))) short short8;
typedef __attribute__((ext_vector_type(4))) float floatx4;

__device__ __forceinline__ float bf2f(unsigned int u) {
    union { unsigned int i; float f; } v; v.i = u << 16; return v.f;
}
__device__ __forceinline__ ushort_t f2bf(float f) {  // RNE
    union { float f; unsigned int i; } v; v.f = f;
    unsigned int x = v.i;
    x += 0x7fffu + ((x >> 16) & 1u);
    return (ushort_t)(x >> 16);
}

__global__ __launch_bounds__(256) void zero_init(float* __restrict__ p, int n) {
    int i = blockIdx.x * 256 + threadIdx.x;
    if (i < n) p[i] = 0.f;
}

// ---------------- weights fp32 -> (hi, lo) bf16 pair ----------------
__global__ __launch_bounds__(256) void convert_split(
    const float* __restrict__ in, ushort_t* __restrict__ hi,
    ushort_t* __restrict__ lo, int n)
{
    int i = blockIdx.x * 256 + threadIdx.x;
    if (i < n) {
        float f = in[i];
        ushort_t h = f2bf(f);
        hi[i] = h;
        lo[i] = f2bf(f - bf2f(h));
    }
}

// ---------------- transpose + split-convert: fp32 [192][16384] -> bf16 [16384][192] hi,lo ----------------
__global__ __launch_bounds__(256) void tconv(
    const float* __restrict__ in, ushort_t* __restrict__ out_hi,
    ushort_t* __restrict__ out_lo, long inStride)
{
    int z = blockIdx.z;
    in += (long)z * inStride;
    out_hi += (long)z * HW * DIM;
    out_lo += (long)z * HW * DIM;
    __shared__ ushort_t th[64][80];
    __shared__ ushort_t tl[64][80];
    int n0 = blockIdx.x * 64, k0 = blockIdx.y * 64;
    int t = threadIdx.x;
#pragma unroll
    for (int i = 0; i < 4; ++i) {
        int kl = (t >> 4) + 16 * i;
        float4 v = *(const float4*)(in + (long)(k0 + kl) * HW + n0 + (t & 15) * 4);
        int nl = (t & 15) * 4;
        ushort_t hx = f2bf(v.x), hy = f2bf(v.y), hz = f2bf(v.z), hw = f2bf(v.w);
        th[nl + 0][kl] = hx; th[nl + 1][kl] = hy;
        th[nl + 2][kl] = hz; th[nl + 3][kl] = hw;
        tl[nl + 0][kl] = f2bf(v.x - bf2f(hx));
        tl[nl + 1][kl] = f2bf(v.y - bf2f(hy));
        tl[nl + 2][kl] = f2bf(v.z - bf2f(hz));
        tl[nl + 3][kl] = f2bf(v.w - bf2f(hw));
    }
    __syncthreads();
#pragma unroll
    for (int i = 0; i < 2; ++i) {
        int nl = t >> 2, seg = (t & 3) + 4 * i;
        *(uint4*)(out_hi + (long)(n0 + nl) * DIM + k0 + seg * 8) = *(uint4*)&th[nl][seg * 8];
        *(uint4*)(out_lo + (long)(n0 + nl) * DIM + k0 + seg * 8) = *(uint4*)&tl[nl][seg * 8];
    }
}

// ---------------- bf16 transpose: [192][16384] -> [16384][192] ----------------
__global__ __launch_bounds__(256) void tconv_b16(
    const ushort_t* __restrict__ in, ushort_t* __restrict__ out)
{
    int z = blockIdx.z;
    in  += (long)z * DIM * HW;
    out += (long)z * HW * DIM;
    __shared__ ushort_t th[64][80];
    int n0 = blockIdx.x * 64, k0 = blockIdx.y * 64;
    int t = threadIdx.x;
#pragma unroll
    for (int i = 0; i < 4; ++i) {
        int kl = (t >> 4) + 16 * i;
        uint2 v = *(const uint2*)(in + (long)(k0 + kl) * HW + n0 + (t & 15) * 4);
        int nl = (t & 15) * 4;
        th[nl + 0][kl] = (ushort_t)(v.x & 0xffffu);
        th[nl + 1][kl] = (ushort_t)(v.x >> 16);
        th[nl + 2][kl] = (ushort_t)(v.y & 0xffffu);
        th[nl + 3][kl] = (ushort_t)(v.y >> 16);
    }
    __syncthreads();
#pragma unroll
    for (int i = 0; i < 2; ++i) {
        int nl = t >> 2, seg = (t & 3) + 4 * i;
        *(uint4*)(out + (long)(n0 + nl) * DIM + k0 + seg * 8) = *(uint4*)&th[nl][seg * 8];
    }
}

// ---------------- register-A MFMA GEMM, K=192 fixed, batched over z ----------------
// Round-1 structure (best measured): BM=64 x BN=128, LDS-staged B, 4 waves 2x2.
#define BS_STRIDE 104
template<int TERMS>
__global__ __launch_bounds__(256) void gemm_reg(
    const ushort_t* __restrict__ Ahi, const ushort_t* __restrict__ Alo,
    const ushort_t* __restrict__ BThi, const ushort_t* __restrict__ BTlo,
    float* __restrict__ C, int M, int N,
    long strideA, long strideB, long strideC)
{
    int z = blockIdx.z;
    Ahi += z * strideA; Alo += z * strideA;
    BThi += z * strideB; BTlo += z * strideB;
    C += z * strideC;
    __shared__ ushort_t Bs0[128 * BS_STRIDE];
    __shared__ ushort_t Bs1[128 * BS_STRIDE];
    int t = threadIdx.x;
    int wave = t >> 6, lane = t & 63;
    int l15 = lane & 15, quad = lane >> 4;
    int m0 = blockIdx.y * 64, n0 = blockIdx.x * 128;
    int wm = (wave & 1) * 32, wn = (wave >> 1) * 64;
    floatx4 acc[2][4];
#pragma unroll
    for (int i = 0; i < 2; ++i)
#pragma unroll
        for (int j = 0; j < 4; ++j) acc[i][j] = (floatx4){0.f, 0.f, 0.f, 0.f};

    if (TERMS == 1) {
        short8 af[2][6];
#pragma unroll
        for (int mi = 0; mi < 2; ++mi)
#pragma unroll
            for (int k0 = 0; k0 < 6; ++k0)
                af[mi][k0] = *(const short8*)(Ahi
                    + (long)(m0 + wm + mi * 16 + l15) * 192 + k0 * 32 + quad * 8);
        for (int i = t; i < 3072; i += 256) {
            int r = i / 24, seg = i % 24;
            uint4 v = *(const uint4*)(BThi + (long)(n0 + r) * 192 + seg * 8);
            ushort_t* dst = (seg < 12) ? &Bs0[r * BS_STRIDE + seg * 8]
                                       : &Bs1[r * BS_STRIDE + (seg - 12) * 8];
            *(uint4*)dst = v;
        }
        __syncthreads();
#pragma unroll
        for (int k0 = 0; k0 < 6; ++k0) {
            int ks = k0 * 32 + quad * 8;
            const ushort_t* buf = (ks < 96) ? Bs0 : Bs1;
            int col = (ks < 96) ? ks : ks - 96;
            short8 bf[4];
#pragma unroll
            for (int ni = 0; ni < 4; ++ni)
                bf[ni] = *(const short8*)&buf[(wn + ni * 16 + l15) * BS_STRIDE + col];
#pragma unroll
            for (int mi = 0; mi < 2; ++mi)
#pragma unroll
                for (int ni = 0; ni < 4; ++ni)
                    acc[mi][ni] = __builtin_amdgcn_mfma_f32_16x16x32_bf16(
                        af[mi][k0], bf[ni], acc[mi][ni], 0, 0, 0);
        }
    } else {
#pragma unroll
        for (int kh = 0; kh < 2; ++kh) {
            short8 ah[2][3], al[2][3];
#pragma unroll
            for (int mi = 0; mi < 2; ++mi)
#pragma unroll
                for (int k0 = 0; k0 < 3; ++k0) {
                    long off = (long)(m0 + wm + mi * 16 + l15) * 192
                             + kh * 96 + k0 * 32 + quad * 8;
                    ah[mi][k0] = *(const short8*)(Ahi + off);
                    al[mi][k0] = *(const short8*)(Alo + off);
                }
            if (kh) __syncthreads();
            for (int i = t; i < 1536; i += 256) {
                int r = i / 12, seg = i % 12;
                long goff = (long)(n0 + r) * 192 + kh * 96 + seg * 8;
                *(uint4*)&Bs0[r * BS_STRIDE + seg * 8] = *(const uint4*)(BThi + goff);
                *(uint4*)&Bs1[r * BS_STRIDE + seg * 8] = *(const uint4*)(BTlo + goff);
            }
            __syncthreads();
#pragma unroll
            for (int k0 = 0; k0 < 3; ++k0) {
                int col = k0 * 32 + quad * 8;
                short8 bh[4], bl[4];
#pragma unroll
                for (int ni = 0; ni < 4; ++ni) {
                    bh[ni] = *(const short8*)&Bs0[(wn + ni * 16 + l15) * BS_STRIDE + col];
                    bl[ni] = *(const short8*)&Bs1[(wn + ni * 16 + l15) * BS_STRIDE + col];
                }
#pragma unroll
                for (int mi = 0; mi < 2; ++mi)
#pragma unroll
                    for (int ni = 0; ni < 4; ++ni) {
                        acc[mi][ni] = __builtin_amdgcn_mfma_f32_16x16x32_bf16(
                            ah[mi][k0], bh[ni], acc[mi][ni], 0, 0, 0);
                        acc[mi][ni] = __builtin_amdgcn_mfma_f32_16x16x32_bf16(
                            ah[mi][k0], bl[ni], acc[mi][ni], 0, 0, 0);
                        acc[mi][ni] = __builtin_amdgcn_mfma_f32_16x16x32_bf16(
                            al[mi][k0], bh[ni], acc[mi][ni], 0, 0, 0);
                    }
            }
        }
    }
#pragma unroll
    for (int mi = 0; mi < 2; ++mi)
#pragma unroll
        for (int ni = 0; ni < 4; ++ni) {
            long base = (long)(m0 + wm + mi * 16 + quad * 4) * N + n0 + wn + ni * 16 + l15;
#pragma unroll
            for (int r = 0; r < 4; ++r)
                C[base + (long)r * N] = acc[mi][ni][r];
        }
}

// ---------------- Depthwise 3x3 + fused sum-of-squares ----------------
// q,k channels (gc < 2*DIM) -> bf16 hi/lo planes [z][384][HW] (feeds MFMA QK^T)
// v channels   (gc >= 2*DIM) -> bf16 vbuf16 [z][192][HW]
__global__ __launch_bounds__(256) void dwconv3x3_lds(
    const float* __restrict__ in, const float* __restrict__ w,
    ushort_t* __restrict__ qk_hi, ushort_t* __restrict__ qk_lo,
    ushort_t* __restrict__ vbuf16, float* __restrict__ normsq,
    int c0, int chunk)
{
    __shared__ float tile[10][132];
    int z = blockIdx.z;
    int cl = blockIdx.y;
    int gc = c0 + cl;
    in  += (long)z * chunk * HW + (long)cl * HW;
    int y0 = blockIdx.x * 8;
    const float* wc = w + gc * 9;
    float wf[9];
#pragma unroll
    for (int i = 0; i < 9; ++i) wf[i] = wc[i];
    int t = threadIdx.x;
    if (t < 10) { tile[t][0] = 0.f; tile[t][129] = 0.f; }
    for (int i = t; i < 320; i += 256) {
        int r = i >> 5, c4 = (i & 31) * 4;
        int gy = y0 - 1 + r;
        float4 v = {0.f, 0.f, 0.f, 0.f};
        if (gy >= 0 && gy < 128) v = *(const float4*)(in + gy * 128 + c4);
        tile[r][1 + c4] = v.x; tile[r][2 + c4] = v.y;
        tile[r][3 + c4] = v.z; tile[r][4 + c4] = v.w;
    }
    __syncthreads();
    int yl = t >> 5, xl = (t & 31) * 4;
    float s0 = 0.f, s1 = 0.f, s2 = 0.f, s3 = 0.f;
#pragma unroll
    for (int r = 0; r < 3; ++r) {
        float c0v = tile[yl + r][xl + 0], c1v = tile[yl + r][xl + 1];
        float c2v = tile[yl + r][xl + 2], c3v = tile[yl + r][xl + 3];
        float c4v = tile[yl + r][xl + 4], c5v = tile[yl + r][xl + 5];
        float w0 = wf[r * 3], w1 = wf[r * 3 + 1], w2 = wf[r * 3 + 2];
        s0 += w0 * c0v + w1 * c1v + w2 * c2v;
        s1 += w0 * c1v + w1 * c2v + w2 * c3v;
        s2 += w0 * c2v + w1 * c3v + w2 * c4v;
        s3 += w0 * c3v + w1 * c4v + w2 * c5v;
    }
    long pix = (long)(y0 + yl) * 128 + xl;
    ushort_t h0 = f2bf(s0), h1 = f2bf(s1), h2 = f2bf(s2), h3 = f2bf(s3);
    uint2 ph;
    ph.x = (unsigned)h0 | ((unsigned)h1 << 16);
    ph.y = (unsigned)h2 | ((unsigned)h3 << 16);
    if (gc < 2 * DIM) {
        ushort_t l0 = f2bf(s0 - bf2f(h0)), l1 = f2bf(s1 - bf2f(h1));
        ushort_t l2 = f2bf(s2 - bf2f(h2)), l3 = f2bf(s3 - bf2f(h3));
        uint2 pl;
        pl.x = (unsigned)l0 | ((unsigned)l1 << 16);
        pl.y = (unsigned)l2 | ((unsigned)l3 << 16);
        long rbase = ((long)z * 384 + gc) * HW + pix;
        *(uint2*)(qk_hi + rbase) = ph;
        *(uint2*)(qk_lo + rbase) = pl;
        __syncthreads();
        float* red = (float*)tile;
        red[t] = s0 * s0 + s1 * s1 + s2 * s2 + s3 * s3;
        __syncthreads();
        for (int off = 128; off > 0; off >>= 1) {
            if (t < off) red[t] += red[t + off];
            __syncthreads();
        }
        if (t == 0) atomicAdd(&normsq[z * 512 + gc], red[0]);
    } else {
        *(uint2*)(vbuf16 + ((long)z * DIM + (gc - 2 * DIM)) * HW + pix) = ph;
    }
}

// ---------------- QK^T partials via MFMA, 3-term bf16 hi/lo ----------------
// grid (NCHUNK, HEADS, BB), block 256 = 4 waves; block covers 256 n-cols,
// each wave 64 cols (2 k-steps of 32). Cross-wave reduce in LDS, one partial/block.
__global__ __launch_bounds__(256) void attn_mfma(
    const ushort_t* __restrict__ qk_hi, const ushort_t* __restrict__ qk_lo,
    float* __restrict__ partial)
{
    int z = blockIdx.z, h = blockIdx.y, pidx = blockIdx.x;
    int t = threadIdx.x;
    int wave = t >> 6, lane = t & 63;
    int l15 = lane & 15, quad = lane >> 4;
    long base = (long)z * 384 * HW;
    const ushort_t* qh = qk_hi + base + (long)(h * CH) * HW;
    const ushort_t* ql = qk_lo + base + (long)(h * CH) * HW;
    const ushort_t* kh = qk_hi + base + (long)(DIM + h * CH) * HW;
    const ushort_t* kl = qk_lo + base + (long)(DIM + h * CH) * HW;
    int ncol0 = pidx * 256 + wave * 64;

    floatx4 acc[3][3];
#pragma unroll
    for (int i = 0; i < 3; ++i)
#pragma unroll
        for (int j = 0; j < 3; ++j) acc[i][j] = (floatx4){0.f, 0.f, 0.f, 0.f};

#pragma unroll
    for (int ks = 0; ks < 2; ++ks) {
        int col = ncol0 + ks * 32 + quad * 8;
        short8 ah[3], al[3], bh[3], bl[3];
#pragma unroll
        for (int i = 0; i < 3; ++i) {
            long ro = (long)(i * 16 + l15) * HW + col;
            ah[i] = *(const short8*)(qh + ro);
            al[i] = *(const short8*)(ql + ro);
            bh[i] = *(const short8*)(kh + ro);
            bl[i] = *(const short8*)(kl + ro);
        }
#pragma unroll
        for (int mi = 0; mi < 3; ++mi)
#pragma unroll
            for (int ni = 0; ni < 3; ++ni) {
                acc[mi][ni] = __builtin_amdgcn_mfma_f32_16x16x32_bf16(
                    ah[mi], bh[ni], acc[mi][ni], 0, 0, 0);
                acc[mi][ni] = __builtin_amdgcn_mfma_f32_16x16x32_bf16(
                    ah[mi], bl[ni], acc[mi][ni], 0, 0, 0);
                acc[mi][ni] = __builtin_amdgcn_mfma_f32_16x16x32_bf16(
                    al[mi], bh[ni], acc[mi][ni], 0, 0, 0);
            }
    }

    // cross-wave reduce: waves 0,1 store into sred[0],sred[1]; waves 2,3 add.
    __shared__ float sred[2][48 * 50];
    float* sb = sred[wave & 1];
    if (wave < 2) {
#pragma unroll
        for (int mi = 0; mi < 3; ++mi)
#pragma unroll
            for (int ni = 0; ni < 3; ++ni)
#pragma unroll
                for (int r = 0; r < 4; ++r)
                    sb[(mi * 16 + quad * 4 + r) * 50 + ni * 16 + l15] = acc[mi][ni][r];
    }
    __syncthreads();
    if (wave >= 2) {
#pragma unroll
        for (int mi = 0; mi < 3; ++mi)
#pragma unroll
            for (int ni = 0; ni < 3; ++ni)
#pragma unroll
                for (int r = 0; r < 4; ++r)
                    sb[(mi * 16 + quad * 4 + r) * 50 + ni * 16 + l15] += acc[mi][ni][r];
    }
    __syncthreads();
    float* pp = partial + ((long)(pidx * 16 + z * HEADS + h)) * 2304;
    for (int i = t; i < 2304; i += 256) {
        int row = i / 48, colo = i - row * 48;
        pp[i] = sred[0][row * 50 + colo] + sred[1][row * 50 + colo];
    }
}

// ---------------- top-k softmax combine: reduce partials inline; wave per row ----------------
// grid (48, BB), block 256 (4 waves = 4 rows)
__global__ __launch_bounds__(256) void topk_combine2(
    const float* __restrict__ partial, const float* __restrict__ normsq,
    const float* __restrict__ temp, const float* __restrict__ attn_w,
    float* __restrict__ Wc)
{
    int z = blockIdx.y;
    int wave = threadIdx.x >> 6, lane = threadIdx.x & 63;
    int rid = blockIdx.x * 4 + wave;   // 0..191 = h*48 + c
    int c = rid % CH, h = rid / CH;
    int d = lane;
    float a = -INFINITY;
    if (d < 48) {
        float s = 0.f;
        const float* pp = partial + (long)(z * HEADS + h) * 2304 + c * CH + d;
        for (int p = 0; p < NCHUNK; ++p) s += pp[(long)p * 16 * 2304];
        float invq = 1.0f / fmaxf(sqrtf(normsq[z * 512 + h * CH + c]), 1e-12f);
        float invk = 1.0f / fmaxf(sqrtf(normsq[z * 512 + DIM + h * CH + d]), 1e-12f);
        a = s * invq * invk * temp[h];
    }
    float m = a;
#pragma unroll
    for (int off = 32; off > 0; off >>= 1) m = fmaxf(m, __shfl_xor(m, off, 64));
    float e = (d < 48) ? expf(a - m) : 0.f;
    int rank = 0;
    for (int j = 0; j < 48; ++j) {
        float aj = __shfl(a, j, 64);
        rank += (aj > a) || (aj == a && j < d);
    }
    // k = int(48*rate) in IEEE double: {24, 32, 36, 38} (48*(2/3) rounds UP to 32.0)
    const int kv[4] = {24, 32, 36, 38};
    float s = 0.f;
#pragma unroll
    for (int i = 0; i < 4; ++i) {
        float contrib = (d < 48 && rank < kv[i]) ? e : 0.f;
#pragma unroll
        for (int off = 32; off > 0; off >>= 1) contrib += __shfl_xor(contrib, off, 64);
        s += (rank < kv[i]) ? attn_w[i] / contrib : 0.f;
    }
    if (d < 48) Wc[(long)z * 9216 + (long)rid * CH + d] = e * s;
}

// ---------------- M[z][o, h*48+d] = sum_ch wproj[o, h*48+ch] * Wc[z][h,ch,d] -> bf16 ----------------
__global__ __launch_bounds__(256) void build_m(
    const float* __restrict__ wproj, const float* __restrict__ Wc,
    ushort_t* __restrict__ Mb)
{
    int z = blockIdx.y;
    int idx = blockIdx.x * 256 + threadIdx.x;
    if (idx >= DIM * DIM) return;
    int cg = idx % DIM;
    int o  = idx / DIM;
    int h = cg / CH, d = cg % CH;
    const float* wp = wproj + o * DIM + h * CH;
    const float* wcc = Wc + (long)z * 9216 + (long)h * CH * CH + d;
    float s = 0.f;
#pragma unroll
    for (int ch = 0; ch < CH; ++ch) s += wp[ch] * wcc[ch * CH];
    Mb[(long)z * DIM * DIM + idx] = f2bf(s);
}

extern "C" void kernel_launch(void* const* d_in, const int* in_sizes, int n_in,
                              void* d_out, int out_size, void* d_ws, size_t ws_size,
                              hipStream_t stream) {
    const float* x      = (const float*)d_in[0];   // [4,192,128,128]
    const float* w_qkv  = (const float*)d_in[1];   // [576,192]
    const float* w_dw   = (const float*)d_in[2];   // [576,9]
    const float* w_proj = (const float*)d_in[3];   // [192,192]
    const float* temper = (const float*)d_in[4];   // [4]
    const float* attn_w = (const float*)d_in[5];   // [4]
    float* out = (float*)d_out;                    // [4,192,128,128]

    // Workspace. Total used ~227 MiB (chunk=192).
    char* p = (char*)d_ws;
    ushort_t* qk_hi  = (ushort_t*)p;   p += (long)BB * 384 * HW * 2;      // 50.3 MB
    ushort_t* qk_lo  = (ushort_t*)p;   p += (long)BB * 384 * HW * 2;      // 50.3 MB
    ushort_t* vbuf16 = (ushort_t*)p;   p += (long)BB * DIM * HW * 2;      // 25.2 MB
    ushort_t* xT_hi  = (ushort_t*)p;   p += (long)BB * HW * DIM * 2;      // 25.2 MB
    ushort_t* xT_lo  = (ushort_t*)p;   p += (long)BB * HW * DIM * 2;      // 25.2 MB
    ushort_t* wq_hi  = (ushort_t*)p;   p += (long)C3 * DIM * 2;
    ushort_t* wq_lo  = (ushort_t*)p;   p += (long)C3 * DIM * 2;
    float* normsq    = (float*)p;      p += (long)BB * 512 * 4;
    float* Wc        = (float*)p;      p += (long)BB * 9216 * 4;
    ushort_t* Mb     = (ushort_t*)p;   p += (long)BB * DIM * DIM * 2;
    float* pre       = (float*)p;      // BB * chunk * HW floats
    float* partial   = pre;            // alias: pre dead before attn_mfma runs (9.4 MB)
    long avail = (long)ws_size - (long)(p - (char*)d_ws);
    int chunk = 64;                                         // 16.8 MB fallback
    if (avail >= (long)BB * 192 * HW * 4) chunk = 192;      // 50.3 MB

    // 0a. zero normsq
    zero_init<<<(BB * 512 + 255) / 256, 256, 0, stream>>>(normsq, BB * 512);
    // 0b. weights -> split bf16
    convert_split<<<(C3 * DIM + 255) / 256, 256, 0, stream>>>(
        w_qkv, wq_hi, wq_lo, C3 * DIM);
    // 0c. x -> xT hi/lo bf16, all batches
    tconv<<<dim3(HW / 64, DIM / 64, BB), 256, 0, stream>>>(
        x, xT_hi, xT_lo, (long)DIM * HW);

    // 1+2. qkv 1x1 MFMA + dwconv3x3(+sumsq). q,k chunks: TERMS=3; v chunks: TERMS=1.
    for (int c0 = 0; c0 < C3; c0 += chunk) {
        if (c0 < 2 * DIM)
            gemm_reg<3><<<dim3(HW / 128, chunk / 64, BB), 256, 0, stream>>>(
                wq_hi + (long)c0 * DIM, wq_lo + (long)c0 * DIM, xT_hi, xT_lo,
                pre, chunk, HW, 0L, (long)HW * DIM, (long)chunk * HW);
        else
            gemm_reg<1><<<dim3(HW / 128, chunk / 64, BB), 256, 0, stream>>>(
                wq_hi + (long)c0 * DIM, wq_hi + (long)c0 * DIM, xT_hi, xT_hi,
                pre, chunk, HW, 0L, (long)HW * DIM, (long)chunk * HW);
        dwconv3x3_lds<<<dim3(16, chunk, BB), 256, 0, stream>>>(
            pre, w_dw, qk_hi, qk_lo, vbuf16, normsq, c0, chunk);
    }
    // 3. QK^T partials via MFMA (no atomics; 64 partials)
    attn_mfma<<<dim3(NCHUNK, HEADS, BB), 256, 0, stream>>>(qk_hi, qk_lo, partial);
    // 4. top-k softmax combine (reduce partials + norms inline)
    topk_combine2<<<dim3(48, BB), 256, 0, stream>>>(
        partial, normsq, temper, attn_w, Wc);
    // 5. fold proj into per-batch [192,192] bf16
    build_m<<<dim3((DIM * DIM + 255) / 256, BB), 256, 0, stream>>>(w_proj, Wc, Mb);
    // 6. v bf16 [ch][pix] -> vT bf16 [pix][ch] (reuse xT_hi)
    tconv_b16<<<dim3(HW / 64, DIM / 64, BB), 256, 0, stream>>>(vbuf16, xT_hi);
    // 7. out = M @ v (MFMA, single term)
    gemm_reg<1><<<dim3(HW / 128, DIM / 64, BB), 256, 0, stream>>>(
        Mb, Mb, xT_hi, xT_hi, out, DIM, HW,
        (long)DIM * DIM, (long)HW * DIM, (long)DIM * HW);
}